// Round 9
// baseline (29.262 us; speedup 1.0000x reference)
//
#include <hip/hip_runtime.h>
#include <hip/hip_bf16.h>

#define NN    64
#define CC    256
#define PP    16
#define FMAP  4096   // CC*PP
#define PCH   256    // part chunks (16 contiguous W_g rows each)

// ---------------------------------------------------------------------------
// K_big: 512 blocks x 256 threads.
//   blocks [0,256):  mv role — block kb owns 16 CONTIGUOUS W_g rows
//                    (256 KB linear slab) and the full 4096-wide partial.
//   blocks [256,512): ub role — dual register-tiled GEMM producing U, Bm
//                    (byte-identical to R7).
// ---------------------------------------------------------------------------
__global__ __launch_bounds__(256) void k_big(const float* __restrict__ x,
                                             const float* __restrict__ We,
                                             const float* __restrict__ be,
                                             const float* __restrict__ Wg,
                                             float* __restrict__ U,
                                             float* __restrict__ Bm,
                                             float* __restrict__ part) {
    __shared__ float smem[3 * 4096];
    const int t = threadIdx.x;

    if (blockIdx.x < 256) {
        // ================= mv role =================
        const int kb = blockIdx.x;           // 16 rows: kb*16 .. kb*16+15

        // inline agg for this block's 16 k's: mean over n of x[n][k]
        {
            const int kl = t & 15, g = t >> 4;   // 16 cols x 16 n-groups
            float s = 0.f;
            #pragma unroll
            for (int nn = 0; nn < 4; ++nn)
                s += x[(size_t)(g * 4 + nn) * FMAP + kb * 16 + kl];
            smem[g * 16 + kl] = s;
        }
        __syncthreads();
        if (t < 16) {
            float s = 0.f;
            #pragma unroll
            for (int g = 0; g < 16; ++g) s += smem[g * 16 + t];
            smem[256 + t] = s * (1.0f / 64.0f);
        }
        __syncthreads();
        const float* aggs = smem + 256;

        // linear 256 KB slab scan: 16 rows x 4 passes of 4 KB
        const float* wp = Wg + (size_t)(kb * 16) * FMAP + t * 4;
        float4 acc[4];
        #pragma unroll
        for (int q = 0; q < 4; ++q) acc[q] = make_float4(0.f, 0.f, 0.f, 0.f);

        #pragma unroll
        for (int r = 0; r < 16; ++r) {
            const float a = aggs[r];
            #pragma unroll
            for (int q = 0; q < 4; ++q) {
                const float4 w = *(const float4*)(wp + (size_t)r * FMAP + q * 1024);
                acc[q].x = fmaf(a, w.x, acc[q].x);
                acc[q].y = fmaf(a, w.y, acc[q].y);
                acc[q].z = fmaf(a, w.z, acc[q].z);
                acc[q].w = fmaf(a, w.w, acc[q].w);
            }
        }
        #pragma unroll
        for (int q = 0; q < 4; ++q)
            *(float4*)&part[(size_t)kb * FMAP + q * 1024 + t * 4] = acc[q];
        return;
    }

    // ================= ub role (R7 verbatim) =================
    const int b    = blockIdx.x - 256;
    const int o0   = (b & 7) * 32;
    const int col0 = (b >> 3) * 32;
    const int n0   = col0 >> 4;

    float* wts = smem;            // [kl][ol] : W1+W2
    float* wt2 = smem + 4096;     // [kl][ol] : W2
    float* xs  = smem + 8192;     // [kl][cl] : X

    const int kq  = t >> 6;
    const int pos = t & 63;
    const int og  = pos >> 3;
    const int cg  = pos & 7;
    const int wol = t >> 3, wseg = t & 7;

    float acc1[4][4] = {{0.f}}, acc2[4][4] = {{0.f}};

    for (int ch = 0; ch < 2; ++ch) {
        const int kb = ch * 128;
        if (ch) __syncthreads();

        {
            const float* wr = We + (size_t)(o0 + wol) * 512 + kb + wseg * 16;
            float w1v[16], w2v[16];
            #pragma unroll
            for (int q = 0; q < 16; q += 4) {
                *(float4*)&w1v[q] = *(const float4*)(wr + q);
                *(float4*)&w2v[q] = *(const float4*)(wr + 256 + q);
            }
            #pragma unroll
            for (int q = 0; q < 16; ++q) {
                int kl = wseg * 16 + q;
                wts[kl * 32 + wol] = w1v[q] + w2v[q];
                wt2[kl * 32 + wol] = w2v[q];
            }
        }
        #pragma unroll
        for (int i = 0; i < 4; ++i) {
            int idx4 = t * 4 + i * 1024;
            int nl = idx4 >> 11, rem = idx4 & 2047;
            int kl = rem >> 4, p = rem & 15;
            float4 v = *(const float4*)&x[(size_t)(n0 + nl) * FMAP + (kb + kl) * PP + p];
            *(float4*)&xs[kl * 32 + nl * 16 + p] = v;
        }
        __syncthreads();

        const int kbase = kq * 32;
        #pragma unroll 8
        for (int kk = 0; kk < 32; ++kk) {
            int k = kbase + kk;
            const float4 a1 = *(const float4*)&wts[k * 32 + og * 4];
            const float4 a2 = *(const float4*)&wt2[k * 32 + og * 4];
            const float4 bx = *(const float4*)&xs [k * 32 + cg * 4];
            const float av1[4] = {a1.x, a1.y, a1.z, a1.w};
            const float av2[4] = {a2.x, a2.y, a2.z, a2.w};
            const float bv [4] = {bx.x, bx.y, bx.z, bx.w};
            #pragma unroll
            for (int i2 = 0; i2 < 4; ++i2)
                #pragma unroll
                for (int j = 0; j < 4; ++j) {
                    acc1[i2][j] = fmaf(av1[i2], bv[j], acc1[i2][j]);
                    acc2[i2][j] = fmaf(av2[i2], bv[j], acc2[i2][j]);
                }
        }
        __syncthreads();
    }

    float* red = smem;
    if (kq > 0) {
        float* dst = red + ((kq - 1) * 64 + pos) * 33;
        #pragma unroll
        for (int i2 = 0; i2 < 4; ++i2)
            #pragma unroll
            for (int j = 0; j < 4; ++j) {
                dst[i2 * 4 + j]      = acc1[i2][j];
                dst[16 + i2 * 4 + j] = acc2[i2][j];
            }
    }
    __syncthreads();
    if (kq == 0) {
        #pragma unroll
        for (int q = 0; q < 3; ++q) {
            const float* s = red + (q * 64 + pos) * 33;
            #pragma unroll
            for (int i2 = 0; i2 < 4; ++i2)
                #pragma unroll
                for (int j = 0; j < 4; ++j) {
                    acc1[i2][j] += s[i2 * 4 + j];
                    acc2[i2][j] += s[16 + i2 * 4 + j];
                }
        }
        const int nl = cg >> 2;
        const int p0 = (cg * 4) & 15;
        const int n  = n0 + nl;
        #pragma unroll
        for (int i2 = 0; i2 < 4; ++i2) {
            const int o = o0 + og * 4 + i2;
            const float bias = be[o];
            const float4 xv = *(const float4*)&x[(size_t)n * FMAP + o * PP + p0];
            float4 uo, bo;
            uo.x = xv.x - acc1[i2][0] - bias;
            uo.y = xv.y - acc1[i2][1] - bias;
            uo.z = xv.z - acc1[i2][2] - bias;
            uo.w = xv.w - acc1[i2][3] - bias;
            bo.x = acc2[i2][0]; bo.y = acc2[i2][1];
            bo.z = acc2[i2][2]; bo.w = acc2[i2][3];
            *(float4*)&U [(size_t)n * FMAP + o * PP + p0] = uo;
            *(float4*)&Bm[(size_t)n * FMAP + o * PP + p0] = bo;
        }
    }
}

// ---------------------------------------------------------------------------
// K_post: 320 blocks x 256 threads.
//   blocks [0,256):  dist role — 4x4 pair tiles (R7 verbatim).
//   blocks [256,320): out role — 64 blocks, 16-way kb-parallel reduction of
//                     the 256 part slices + bias + broadcast.
// ---------------------------------------------------------------------------
__global__ __launch_bounds__(256) void k_post(const float* __restrict__ U,
                                              const float* __restrict__ Bm,
                                              const float* __restrict__ part,
                                              const float* __restrict__ bg,
                                              float* __restrict__ out,
                                              float* __restrict__ edges) {
    const int t = threadIdx.x;
    if (blockIdx.x < 256) {
        const int i0 = (blockIdx.x >> 4) * 4;
        const int j0 = (blockIdx.x & 15) * 4;

        float acc[4][4] = {{0.f}};
        #pragma unroll
        for (int s = 0; s < 4; ++s) {
            const int m = s * 1024 + t * 4;
            float4 u[4], b[4];
            #pragma unroll
            for (int jl = 0; jl < 4; ++jl) u[jl] = *(const float4*)&U [(size_t)(j0 + jl) * FMAP + m];
            #pragma unroll
            for (int il = 0; il < 4; ++il) b[il] = *(const float4*)&Bm[(size_t)(i0 + il) * FMAP + m];
            #pragma unroll
            for (int il = 0; il < 4; ++il)
                #pragma unroll
                for (int jl = 0; jl < 4; ++jl) {
                    acc[il][jl] += fabsf(u[jl].x - b[il].x) + fabsf(u[jl].y - b[il].y)
                                 + fabsf(u[jl].z - b[il].z) + fabsf(u[jl].w - b[il].w);
                }
        }
        #pragma unroll
        for (int il = 0; il < 4; ++il)
            #pragma unroll
            for (int jl = 0; jl < 4; ++jl) {
                float v = acc[il][jl];
                #pragma unroll
                for (int msk = 1; msk < 64; msk <<= 1) v += __shfl_xor(v, msk, 64);
                acc[il][jl] = v;
            }
        __shared__ float wred[4][16];
        const int w = t >> 6;
        if ((t & 63) == 0) {
            #pragma unroll
            for (int il = 0; il < 4; ++il)
                #pragma unroll
                for (int jl = 0; jl < 4; ++jl) wred[w][il * 4 + jl] = acc[il][jl];
        }
        __syncthreads();
        if (t < 16) {
            const int il = t >> 2, jl = t & 3;
            const int i = i0 + il, j = j0 + jl;
            float v = wred[0][t] + wred[1][t] + wred[2][t] + wred[3][t];
            edges[i * 64 + j] = (i == j) ? 1.0f : v;
        }
    } else {
        // out role: 64 blocks; block mb owns cols [mb*64, mb*64+64).
        const int mb = blockIdx.x - 256;      // 0..63
        const int kg = t >> 4;                // 16 groups over part slices
        const int ml = t & 15;                // 16 float4 cols
        const float* pp = part + (size_t)kg * 16 * FMAP + mb * 64 + ml * 4;
        float4 s = make_float4(0.f, 0.f, 0.f, 0.f);
        #pragma unroll
        for (int r = 0; r < 16; ++r) {
            const float4 v = *(const float4*)(pp + (size_t)r * FMAP);
            s.x += v.x; s.y += v.y; s.z += v.z; s.w += v.w;
        }
        __shared__ float4 red4[16][16];
        __shared__ float4 rst4[16];
        red4[kg][ml] = s;
        __syncthreads();
        if (t < 16) {
            const float4 bgv = *(const float4*)&bg[mb * 64 + t * 4];
            float4 r = bgv;
            #pragma unroll
            for (int g = 0; g < 16; ++g) {
                const float4 v = red4[g][t];
                r.x += v.x; r.y += v.y; r.z += v.z; r.w += v.w;
            }
            rst4[t] = r;
        }
        __syncthreads();
        const int c  = t & 15;       // float4 col within the 64-col chunk
        const int n0 = (t >> 4) * 4; // 16 groups x 4 n's
        const float4 v = rst4[c];
        #pragma unroll
        for (int i = 0; i < 4; ++i)
            *(float4*)&out[(size_t)(n0 + i) * FMAP + mb * 64 + c * 4] = v;
    }
}

extern "C" void kernel_launch(void* const* d_in, const int* in_sizes, int n_in,
                              void* d_out, int out_size, void* d_ws, size_t ws_size,
                              hipStream_t stream) {
    const float* x  = (const float*)d_in[0];   // (64,1,256,4,4)
    const float* We = (const float*)d_in[1];   // (256,512)
    const float* be = (const float*)d_in[2];   // (256,)
    const float* Wg = (const float*)d_in[3];   // (4096,4096)
    const float* bg = (const float*)d_in[4];   // (4096,)
    float* out   = (float*)d_out;
    float* edges = out + (size_t)NN * FMAP;

    float* ws   = (float*)d_ws;
    float* U    = ws;                        // 262144 floats (1 MB)
    float* Bm   = U + (size_t)NN * FMAP;     // 262144 floats (1 MB)
    float* part = Bm + (size_t)NN * FMAP;    // PCH*FMAP = 1,048,576 floats (4 MB)

    k_big <<<dim3(512), 256, 0, stream>>>(x, We, be, Wg, U, Bm, part);
    k_post<<<dim3(320), 256, 0, stream>>>(U, Bm, part, bg, out, edges);
}